// Round 8
// baseline (1846.127 us; speedup 1.0000x reference)
//
#include <hip/hip_runtime.h>
#include <hip/hip_bf16.h>

typedef __hip_bfloat16 bf16;
typedef __attribute__((ext_vector_type(8))) short bf16x8;
typedef __attribute__((ext_vector_type(4))) float f32x4;
#define DEV __device__ __forceinline__

constexpr int SEQ  = 4096;
constexpr int NB   = 4;
constexpr int NTOK = NB * SEQ;          // 16384 tokens
constexpr float EPS = 1e-5f;
constexpr int NCH = 64;                 // scan chunk length
constexpr int NCHUNK = SEQ / NCH;       // 64 chunks/seq
constexpr float LOG2E = 1.44269504f;
constexpr int MAGIC = 0x3C7A55E1;       // != 0xAAAAAAAA ws poison

// ---------------- workspace layout (float offsets) ----------------
constexpr int OFF_WDT  = 0;                    // f32 [8][256] dt_proj^T
constexpr int OFF_WB   = 2048;                 // bf16 weight area (151552 shorts)
constexpr int WB_IP = 0;                       // [128][64]
constexpr int WB_WP = 8192;                    // [128][64]
constexpr int WB_FP = 16384;                   // [128][128]
constexpr int WB_PR = 32768;                   // [512][128]
constexpr int WB_MO = 98304;                   // [128][256]
constexpr int WB_OP = 131072;                  // [64][128]
constexpr int WB_XP = 139264;                  // [48][256] (40 real + 8 zero rows)
constexpr int WB_TOT = 151552;
constexpr int OFF_XDBL = OFF_WB + WB_TOT / 2;        // f32 [NTOK][40] (655360 f)
constexpr int OFF_R1   = OFF_XDBL + NTOK * 40;       // H states [4096][256] f32 (1048576 f)
constexpr int OFF_WSW  = OFF_R1   + 1048576;         // bf16 NTOK*128  -> 1048576 f
constexpr int OFF_U    = OFF_WSW  + 1048576;         // bf16 NTOK*128  -> 1048576 f
constexpr int OFF_R2   = OFF_U    + 1048576;         // xpre (2097152 f)
constexpr int OFF_SILUZ= OFF_R2   + 2097152;         // bf16 NTOK*256  -> 2097152 f
constexpr int OFF_XC   = OFF_SILUZ+ 2097152;         // bf16 NTOK*256
constexpr int OFF_G    = OFF_XC   + 2097152;         // bf16 NTOK*256
constexpr int OFF_FLAG = OFF_G    + 2097152;         // int dtype flag
constexpr int OFF_CNT  = OFF_FLAG + 4;               // int ticket counter
constexpr int OFF_SFLAG= OFF_FLAG + 8;               // int [4096] chain flags

DEV float b2f(bf16 x) { return __bfloat162float(x); }
DEV bf16 f2b(float x) { return __float2bfloat16(x); }
DEV short shof(bf16 h) { short s; __builtin_memcpy(&s, &h, 2); return s; }
DEV float ldin(const void* p, int i, int f) {
  return f ? ((const float*)p)[i] : b2f(((const bf16*)p)[i]);
}
DEV unsigned pack2(float a, float b) {
  bf16 ha = f2b(a), hb = f2b(b);
  unsigned short ua, ub;
  __builtin_memcpy(&ua, &ha, 2); __builtin_memcpy(&ub, &hb, 2);
  return (unsigned)ua | ((unsigned)ub << 16);
}
DEV float lo16f(unsigned u) { return __int_as_float((int)(u << 16)); }
DEV float hi16f(unsigned u) { return __int_as_float((int)(u & 0xffff0000u)); }
template<int CTRL>
DEV float dpp_add(float v) {
  int r = __builtin_amdgcn_update_dpp(0, __float_as_int(v), CTRL, 0xF, 0xF, false);
  return v + __int_as_float(r);
}
DEV float exp2f_fast(float a) { return __builtin_amdgcn_exp2f(a); }
DEV float softplus(float a) {
  return (a > 20.f) ? a : __logf(1.f + exp2f_fast(a * LOG2E));
}
DEV float silu(float a) { return a / (1.f + __expf(-a)); }

// ---------------- prep: dtype detect + bf16 weight copies + WDT f32 + ticket zero ----------------
DEV void cpw(int e, int base, int count, const void* __restrict__ src,
             bf16* __restrict__ wb, int f) {
  int r = e - base;
  if (r >= 0 && r < count) wb[base + r] = f2b(ldin(src, r, f));
}
__global__ __launch_bounds__(256) void prep_k(
    const void* __restrict__ w_ip, const void* __restrict__ w_wp, const void* __restrict__ w_fp,
    const void* __restrict__ w_pr, const void* __restrict__ w_mo, const void* __restrict__ w_op,
    const void* __restrict__ w_x,  const void* __restrict__ w_dt,
    const void* __restrict__ x, float* __restrict__ wsf, int* __restrict__ flagp,
    int* __restrict__ counter)
{
  __shared__ int cnt;
  if (threadIdx.x == 0) cnt = 0;
  __syncthreads();
  {
    float v = b2f(((const bf16*)x)[threadIdx.x]);
    int ok = (v == v) && fabsf(v) > 1e-4f && fabsf(v) < 100.f;
    atomicAdd(&cnt, ok);
  }
  __syncthreads();
  int f = (cnt > 204) ? 0 : 1;
  if (blockIdx.x == 0 && threadIdx.x == 0) { *flagp = f; *counter = 0; }

  int e = blockIdx.x * 256 + threadIdx.x;   // 592*256 covers 151552
  bf16* wb = (bf16*)(wsf + OFF_WB);
  cpw(e, WB_IP, 8192,  w_ip, wb, f);
  cpw(e, WB_WP, 8192,  w_wp, wb, f);
  cpw(e, WB_FP, 16384, w_fp, wb, f);
  cpw(e, WB_PR, 65536, w_pr, wb, f);
  cpw(e, WB_MO, 32768, w_mo, wb, f);
  cpw(e, WB_OP, 8192,  w_op, wb, f);
  {
    int r = e - WB_XP;
    if (r >= 0 && r < 12288) wb[WB_XP + r] = (r < 10240) ? f2b(ldin(w_x, r, f)) : f2b(0.f);
  }
  if (e < 2048) {
    int r = e >> 8, d = e & 255;
    wsf[OFF_WDT + e] = ldin(w_dt, d * 8 + r, f);
  }
}

// ---------------- fm: rms1 + ip/wp GEMMs + fp GEMM + in_proj GEMM (unchanged R7) ----------------
__global__ __launch_bounds__(256) void fm_k(
    const void* __restrict__ x, const void* __restrict__ w1, const float* __restrict__ wsf,
    const void* __restrict__ b_ip, const void* __restrict__ b_wp, const void* __restrict__ b_fp,
    bf16* __restrict__ wsw, bf16* __restrict__ u, bf16* __restrict__ xpre,
    bf16* __restrict__ siluz, const int* __restrict__ flagp)
{
  __shared__ short xn[32 * 72];
  __shared__ short t1[32 * 136];
  __shared__ short ul[32 * 136];
  const int f = *flagp;
  const int tid = threadIdx.x;
  const int tok0 = blockIdx.x * 32;
  {  // rms1: 8 threads/token, 8 ch each
    const int token = tid >> 3, r = tid & 7;
    float v[8]; float ss = 0.f;
    #pragma unroll
    for (int k = 0; k < 8; ++k) {
      v[k] = ldin(x, (tok0 + token) * 64 + r * 8 + k, f);
      ss += v[k] * v[k];
    }
    ss += __shfl_xor(ss, 1, 8); ss += __shfl_xor(ss, 2, 8); ss += __shfl_xor(ss, 4, 8);
    float sc = rsqrtf(ss * (1.f / 64.f) + EPS);
    unsigned* dst = (unsigned*)xn + token * 36 + r * 4;
    #pragma unroll
    for (int k = 0; k < 4; ++k) {
      int i = r * 8 + k * 2;
      dst[k] = pack2(v[k*2] * sc * ldin(w1, i, f), v[k*2+1] * sc * ldin(w1, i + 1, f));
    }
  }
  __syncthreads();
  const int lane = tid & 63, m = lane & 15, q = lane >> 4;
  const int w = tid >> 6;
  {  // GEMM1/1b: K=64, N=128 each. waves 0,1 -> Wip (t1), 2,3 -> Wwp (wsw)
    const int wt = w >> 1, ng = w & 1;
    const bf16* W = (const bf16*)(wsf + OFF_WB) + (wt ? WB_WP : WB_IP);
    const void* bia = wt ? b_wp : b_ip;
    bf16x8 a[2][2];
    #pragma unroll
    for (int mt = 0; mt < 2; ++mt)
      #pragma unroll
      for (int kk = 0; kk < 2; ++kk)
        a[mt][kk] = *(const bf16x8*)&xn[(mt * 16 + m) * 72 + kk * 32 + q * 8];
    #pragma unroll
    for (int nti = 0; nti < 4; ++nti) {
      int nt = ng * 4 + nti;
      int n = nt * 16 + m;
      f32x4 acc[2] = {{0,0,0,0},{0,0,0,0}};
      #pragma unroll
      for (int kk = 0; kk < 2; ++kk) {
        bf16x8 b = *(const bf16x8*)(W + (nt * 16 + m) * 64 + kk * 32 + q * 8);
        #pragma unroll
        for (int mt = 0; mt < 2; ++mt)
          acc[mt] = __builtin_amdgcn_mfma_f32_16x16x32_bf16(a[mt][kk], b, acc[mt], 0, 0, 0);
      }
      float bv = ldin(bia, n, f);
      #pragma unroll
      for (int mt = 0; mt < 2; ++mt)
        #pragma unroll
        for (int r = 0; r < 4; ++r) {
          float v = acc[mt][r] + bv;
          if (wt) wsw[(tok0 + mt * 16 + q * 4 + r) * 128 + n] = f2b(silu(v));
          else    t1[(mt * 16 + q * 4 + r) * 136 + n] = shof(f2b(v));
        }
    }
  }
  __syncthreads();
  {  // GEMM2: u = t1@Wfp^T + b_fp. K=128, N=128; wave w -> nt {2w, 2w+1}
    const bf16* WF = (const bf16*)(wsf + OFF_WB) + WB_FP;
    bf16x8 a[2][4];
    #pragma unroll
    for (int mt = 0; mt < 2; ++mt)
      #pragma unroll
      for (int kk = 0; kk < 4; ++kk)
        a[mt][kk] = *(const bf16x8*)&t1[(mt * 16 + m) * 136 + kk * 32 + q * 8];
    #pragma unroll
    for (int nti = 0; nti < 2; ++nti) {
      int nt = w * 2 + nti;
      int n = nt * 16 + m;
      f32x4 acc[2] = {{0,0,0,0},{0,0,0,0}};
      #pragma unroll
      for (int kk = 0; kk < 4; ++kk) {
        bf16x8 b = *(const bf16x8*)(WF + (nt * 16 + m) * 128 + kk * 32 + q * 8);
        #pragma unroll
        for (int mt = 0; mt < 2; ++mt)
          acc[mt] = __builtin_amdgcn_mfma_f32_16x16x32_bf16(a[mt][kk], b, acc[mt], 0, 0, 0);
      }
      float bv = ldin(b_fp, n, f);
      #pragma unroll
      for (int mt = 0; mt < 2; ++mt)
        #pragma unroll
        for (int r = 0; r < 4; ++r) {
          bf16 h = f2b(acc[mt][r] + bv);
          ul[(mt * 16 + q * 4 + r) * 136 + n] = shof(h);
          u[(tok0 + mt * 16 + q * 4 + r) * 128 + n] = h;
        }
    }
  }
  __syncthreads();
  {  // GEMM3: xz = u@Wpr^T. K=128, N=512; wave w -> nt [8w, 8w+8)
    const bf16* WP = (const bf16*)(wsf + OFF_WB) + WB_PR;
    bf16x8 a[2][4];
    #pragma unroll
    for (int mt = 0; mt < 2; ++mt)
      #pragma unroll
      for (int kk = 0; kk < 4; ++kk)
        a[mt][kk] = *(const bf16x8*)&ul[(mt * 16 + m) * 136 + kk * 32 + q * 8];
    #pragma unroll
    for (int nti = 0; nti < 8; ++nti) {
      int nt = w * 8 + nti;
      int n = nt * 16 + m;
      f32x4 acc[2] = {{0,0,0,0},{0,0,0,0}};
      #pragma unroll
      for (int kk = 0; kk < 4; ++kk) {
        bf16x8 b = *(const bf16x8*)(WP + (nt * 16 + m) * 128 + kk * 32 + q * 8);
        #pragma unroll
        for (int mt = 0; mt < 2; ++mt)
          acc[mt] = __builtin_amdgcn_mfma_f32_16x16x32_bf16(a[mt][kk], b, acc[mt], 0, 0, 0);
      }
      #pragma unroll
      for (int mt = 0; mt < 2; ++mt)
        #pragma unroll
        for (int r = 0; r < 4; ++r) {
          int tok = tok0 + mt * 16 + q * 4 + r;
          if (n < 256) xpre[tok * 256 + n] = f2b(acc[mt][r]);
          else         siluz[tok * 256 + (n - 256)] = f2b(silu(acc[mt][r]));
        }
    }
  }
}

// ---------------- conv + x_proj MFMA; xdbl written with B/C interleaved ----------------
// xdbl col map: dt_r -> r (r<8); B_j -> 8+2j; C_j -> 9+2j
__global__ __launch_bounds__(256) void conv_k(
    const bf16* __restrict__ xpre, const void* __restrict__ cw, const void* __restrict__ cb,
    const float* __restrict__ wsf, bf16* __restrict__ xc, float* __restrict__ xdbl,
    const int* __restrict__ flagp)
{
  __shared__ short xh[35 * 256];
  __shared__ short cs[32 * 264];
  const int f = *flagp;
  const int tid = threadIdx.x;
  const int tok0 = blockIdx.x * 32;
  const bool seqstart = (tok0 & (SEQ - 1)) == 0;
  for (int c = tid; c < 1120; c += 256) {
    int e0 = c * 8;
    int tt = e0 >> 8, i = e0 & 255;
    int gtok = tok0 + tt - 3;
    uint4* dst = (uint4*)(xh + e0);
    if (gtok >= 0 && !(seqstart && tt < 3)) *dst = *(const uint4*)(xpre + gtok * 256 + i);
    else                                    *dst = make_uint4(0, 0, 0, 0);
  }
  __syncthreads();
  {
    const int ch0 = (tid & 63) * 4;
    const int t0 = (tid >> 6) * 8;
    float w4[4][4], cb4[4];
    #pragma unroll
    for (int c = 0; c < 4; ++c) {
      cb4[c] = ldin(cb, ch0 + c, f);
      #pragma unroll
      for (int k = 0; k < 4; ++k) w4[c][k] = ldin(cw, (ch0 + c) * 4 + k, f);
    }
    float win[11][4];
    #pragma unroll
    for (int r = 0; r < 11; ++r) {
      uint2 v = *(const uint2*)&xh[(t0 + r) * 256 + ch0];
      win[r][0] = lo16f(v.x); win[r][1] = hi16f(v.x);
      win[r][2] = lo16f(v.y); win[r][3] = hi16f(v.y);
    }
    #pragma unroll
    for (int t = 0; t < 8; ++t) {
      unsigned pk[2];
      #pragma unroll
      for (int cp = 0; cp < 2; ++cp) {
        float o[2];
        #pragma unroll
        for (int ci = 0; ci < 2; ++ci) {
          int c = cp * 2 + ci;
          float acc = cb4[c];
          #pragma unroll
          for (int k = 0; k < 4; ++k) acc = fmaf(win[t + k][c], w4[c][k], acc);
          o[ci] = silu(acc);
        }
        pk[cp] = pack2(o[0], o[1]);
      }
      uint2 pv = make_uint2(pk[0], pk[1]);
      *(uint2*)&cs[(t0 + t) * 264 + ch0] = pv;
      *(uint2*)(xc + (tok0 + t0 + t) * 256 + ch0) = pv;
    }
  }
  __syncthreads();
  const int w = tid >> 6;
  if (w < 2) {
    const bf16* Wx = (const bf16*)(wsf + OFF_WB) + WB_XP;
    const int lane = tid & 63, m = lane & 15, quad = lane >> 4;
    f32x4 acc[3] = {{0,0,0,0},{0,0,0,0},{0,0,0,0}};
    #pragma unroll
    for (int k0 = 0; k0 < 256; k0 += 32) {
      bf16x8 af = *(const bf16x8*)&cs[(w * 16 + m) * 264 + k0 + quad * 8];
      #pragma unroll
      for (int nt = 0; nt < 3; ++nt) {
        bf16x8 bfr = *(const bf16x8*)(Wx + (nt * 16 + m) * 256 + k0 + quad * 8);
        acc[nt] = __builtin_amdgcn_mfma_f32_16x16x32_bf16(af, bfr, acc[nt], 0, 0, 0);
      }
    }
    #pragma unroll
    for (int nt = 0; nt < 3; ++nt) {
      int n = nt * 16 + m;
      if (n < 40) {
        int col = (n < 8) ? n : ((n < 24) ? (2 * n - 8) : (2 * n - 39));
        #pragma unroll
        for (int r = 0; r < 4; ++r)
          xdbl[(tok0 + w * 16 + quad * 4 + r) * 40 + col] = acc[nt][r];
      }
    }
  }
}

// ---------------- single-pass chained scan (ticket-ordered, deadlock-free) ----------------
// grid 4096 (1-D). ticket -> chunk c = t>>6 (c-major => predecessor scheduled first), seq = t&63.
__global__ __launch_bounds__(256) void scan1_k(
    const float* __restrict__ xdbl, const bf16* __restrict__ xc, const bf16* __restrict__ siluz,
    const void* __restrict__ A_log, const void* __restrict__ D_par, const void* __restrict__ dt_b,
    const float* __restrict__ WDT, float* __restrict__ hin, int* __restrict__ sflag,
    int* __restrict__ counter, bf16* __restrict__ g, const int* __restrict__ flagp)
{
  __shared__ float dt_l[NCH * 8];
  __shared__ float dx_l[NCH * 16 * 2];
  __shared__ float bc_l[NCH * 16 * 2];
  __shared__ float g_l[NCH * 16];
  __shared__ int tick_s;
  const int f = *flagp;
  const int tid = threadIdx.x;
  if (tid == 0) tick_s = atomicAdd(counter, 1);
  __syncthreads();
  const int ticket = tick_s;
  const int c = ticket >> 6, seq = ticket & 63;
  const int bb = seq >> 4, dg = seq & 15;
  const int dl = tid >> 4, s = tid & 15;
  const int j = s;
  const int d_loop = dg * 16 + dl;
  const int d_stg  = dg * 16 + j;
  const int tok_base = bb * SEQ + c * NCH;

  const float Aval2 = -__expf(ldin(A_log, d_loop * 16 + s, f)) * LOG2E;
  const float Dp = ldin(D_par, d_loop, f);
  const float dtb_j = ldin(dt_b, d_stg, f);
  float wdt[8];
  #pragma unroll
  for (int r = 0; r < 8; ++r) wdt[r] = WDT[r * 256 + d_stg];

  // ---- stage (once) ----
  for (int e2 = tid * 4; e2 < NCH * 8; e2 += 1024)
    *(float4*)(dt_l + e2) = *(const float4*)(xdbl + (tok_base + (e2 >> 3)) * 40 + (e2 & 7));
  #pragma unroll
  for (int k = 0; k < 4; ++k) {
    int e = tid + k * 256;
    int t = e >> 4;
    *(float2*)(bc_l + e * 2) = *(const float2*)(xdbl + (tok_base + t) * 40 + 8 + 2 * j);
  }
  __syncthreads();
  #pragma unroll
  for (int k = 0; k < 4; ++k) {
    int e = tid + k * 256;
    int t = e >> 4;
    float a = dtb_j;
    #pragma unroll
    for (int r = 0; r < 8; ++r) a = fmaf(dt_l[t * 8 + r], wdt[r], a);
    float xcv = b2f(xc[(tok_base + t) * 256 + d_stg]);
    *(float2*)(dx_l + e * 2) = make_float2(softplus(a), xcv);
  }
  __syncthreads();

  // ---- local A loop (h from 0, aP via sum of delta) ----
  float h = 0.f, sdlt = 0.f;
  #pragma unroll 8
  for (int t = 0; t < NCH; ++t) {
    float2 dx = *(const float2*)(dx_l + (t * 16 + dl) * 2);
    float dA = exp2f_fast(dx.x * Aval2);
    sdlt += dx.x;
    h = fmaf(dA, h, dx.x * dx.y * bc_l[(t * 16 + s) * 2]);
  }
  float aP = exp2f_fast(Aval2 * sdlt);

  // ---- chain: poll H_c, publish H_{c+1} BEFORE the heavy C loop ----
  const int slot = seq * 64 + c;
  float Hc = 0.f;
  if (c > 0) {
    if (tid == 0) {
      int spin = 0;
      while (__hip_atomic_load(&sflag[slot], __ATOMIC_ACQUIRE, __HIP_MEMORY_SCOPE_AGENT) != MAGIC) {
        __builtin_amdgcn_s_sleep(2);
        if (++spin > (1 << 24)) break;   // pathological bail: fail fast, never hang
      }
    }
    __syncthreads();
    Hc = __hip_atomic_load(&hin[slot * 256 + tid], __ATOMIC_RELAXED, __HIP_MEMORY_SCOPE_AGENT);
  }
  if (c < 63) {
    float Hn = fmaf(aP, Hc, h);
    __hip_atomic_store(&hin[(slot + 1) * 256 + tid], Hn, __ATOMIC_RELAXED, __HIP_MEMORY_SCOPE_AGENT);
    __syncthreads();
    if (tid == 0)
      __hip_atomic_store(&sflag[slot + 1], MAGIC, __ATOMIC_RELEASE, __HIP_MEMORY_SCOPE_AGENT);
  }

  // ---- C loop: replay from Hc, emit y (LDS still staged) ----
  h = Hc;
  #pragma unroll 8
  for (int t = 0; t < NCH; ++t) {
    float2 dx = *(const float2*)(dx_l + (t * 16 + dl) * 2);
    float dA = exp2f_fast(dx.x * Aval2);
    float du = dx.x * dx.y;
    float2 bc = *(const float2*)(bc_l + (t * 16 + s) * 2);
    h = fmaf(dA, h, du * bc.x);
    float p = h * bc.y;
    p = dpp_add<0x121>(p);
    p = dpp_add<0x122>(p);
    p = dpp_add<0x124>(p);
    p = dpp_add<0x128>(p);
    if (s == 0) g_l[t * 16 + dl] = p + dx.y * Dp;
  }
  __syncthreads();
  #pragma unroll
  for (int k = 0; k < 4; ++k) {
    int e = tid + k * 256;
    int t = e >> 4;
    int tok = tok_base + t;
    g[tok * 256 + d_stg] = f2b(g_l[e] * b2f(siluz[tok * 256 + d_stg]));
  }
}

// ---------------- back: m = g@Wmo^T ; rms2+u, gate wsw ; @Wop^T + b + resid (unchanged R7) ----------------
__global__ __launch_bounds__(256) void back_k(
    const bf16* __restrict__ g, const float* __restrict__ wsf, const void* __restrict__ w2,
    const bf16* __restrict__ u, const bf16* __restrict__ wsw, const void* __restrict__ b_op,
    const void* __restrict__ x, void* __restrict__ out, const int* __restrict__ flagp)
{
  __shared__ short ms[32 * 136];
  const int f = *flagp;
  const int tid = threadIdx.x;
  const int tok0 = blockIdx.x * 32;
  const int lane = tid & 63, m = lane & 15, q = lane >> 4;
  const int w = tid >> 6;
  const bf16* WM = (const bf16*)(wsf + OFF_WB) + WB_MO;
  const bf16* WO = (const bf16*)(wsf + OFF_WB) + WB_OP;
  {  // phase 1: m = g@Wmo^T (K=256, N=128); wave w -> nt {2w, 2w+1}
    f32x4 acc[2][2] = {{{0,0,0,0},{0,0,0,0}},{{0,0,0,0},{0,0,0,0}}};
    #pragma unroll
    for (int kk = 0; kk < 8; ++kk) {
      bf16x8 a0 = *(const bf16x8*)(g + (tok0 + m) * 256 + kk * 32 + q * 8);
      bf16x8 a1 = *(const bf16x8*)(g + (tok0 + 16 + m) * 256 + kk * 32 + q * 8);
      #pragma unroll
      for (int nti = 0; nti < 2; ++nti) {
        int nt = w * 2 + nti;
        bf16x8 b = *(const bf16x8*)(WM + (nt * 16 + m) * 256 + kk * 32 + q * 8);
        acc[nti][0] = __builtin_amdgcn_mfma_f32_16x16x32_bf16(a0, b, acc[nti][0], 0, 0, 0);
        acc[nti][1] = __builtin_amdgcn_mfma_f32_16x16x32_bf16(a1, b, acc[nti][1], 0, 0, 0);
      }
    }
    #pragma unroll
    for (int nti = 0; nti < 2; ++nti) {
      int n = (w * 2 + nti) * 16 + m;
      #pragma unroll
      for (int mt = 0; mt < 2; ++mt)
        #pragma unroll
        for (int r = 0; r < 4; ++r)
          ms[(mt * 16 + q * 4 + r) * 136 + n] = shof(f2b(acc[nti][mt][r]));
    }
  }
  __syncthreads();
  {  // rms2 + u residual + wsw gate (8 threads/token, 16 ch each)
    const int token = tid >> 3, r = tid & 7;
    float mv[16]; float ss = 0.f;
    #pragma unroll
    for (int k = 0; k < 16; ++k) {
      mv[k] = b2f(((const bf16*)ms)[token * 136 + r * 16 + k]);
      ss += mv[k] * mv[k];
    }
    ss += __shfl_xor(ss, 1, 8); ss += __shfl_xor(ss, 2, 8); ss += __shfl_xor(ss, 4, 8);
    float sc = rsqrtf(ss * (1.f / 128.f) + EPS);
    #pragma unroll
    for (int k = 0; k < 16; ++k) {
      int i = r * 16 + k;
      int ga = (tok0 + token) * 128 + i;
      float v = mv[k] * sc * ldin(w2, i, f) + b2f(u[ga]);
      ms[token * 136 + i] = shof(f2b(v * b2f(wsw[ga])));
    }
  }
  __syncthreads();
  {  // phase 2: out = ms@Wop^T + b_op + resid (K=128, N=64); wave w -> nt w
    bf16x8 a[2][4];
    #pragma unroll
    for (int mt = 0; mt < 2; ++mt)
      #pragma unroll
      for (int kk = 0; kk < 4; ++kk)
        a[mt][kk] = *(const bf16x8*)&ms[(mt * 16 + m) * 136 + kk * 32 + q * 8];
    int nt = w;
    f32x4 acc[2] = {{0,0,0,0},{0,0,0,0}};
    #pragma unroll
    for (int kk = 0; kk < 4; ++kk) {
      bf16x8 b = *(const bf16x8*)(WO + (nt * 16 + m) * 128 + kk * 32 + q * 8);
      #pragma unroll
      for (int mt = 0; mt < 2; ++mt)
        acc[mt] = __builtin_amdgcn_mfma_f32_16x16x32_bf16(a[mt][kk], b, acc[mt], 0, 0, 0);
    }
    int n = nt * 16 + m;
    float bv = ldin(b_op, n, f);
    #pragma unroll
    for (int mt = 0; mt < 2; ++mt)
      #pragma unroll
      for (int r = 0; r < 4; ++r) {
        int token = tok0 + mt * 16 + q * 4 + r;
        float v = acc[mt][r] + bv + ldin(x, token * 64 + n, f);
        if (f) ((float*)out)[token * 64 + n] = v;
        else   ((bf16*)out)[token * 64 + n] = f2b(v);
      }
  }
}

// ---------------- launch ----------------
extern "C" void kernel_launch(void* const* d_in, const int* in_sizes, int n_in,
                              void* d_out, int out_size, void* d_ws, size_t ws_size,
                              hipStream_t stream) {
  (void)in_sizes; (void)n_in; (void)out_size; (void)ws_size;
  const void* x        = d_in[0];
  const void* w_norm1  = d_in[1];
  const void* w_norm2  = d_in[2];
  const void* W_ip     = d_in[3];
  const void* b_ip     = d_in[4];
  const void* W_fp     = d_in[5];
  const void* b_fp     = d_in[6];
  const void* W_wp     = d_in[7];
  const void* b_wp     = d_in[8];
  const void* W_op     = d_in[9];
  const void* b_op     = d_in[10];
  const void* in_proj  = d_in[11];
  const void* conv_w   = d_in[12];
  const void* conv_b   = d_in[13];
  const void* x_proj   = d_in[14];
  const void* dt_projw = d_in[15];
  const void* dt_projb = d_in[16];
  const void* A_log    = d_in[17];
  const void* D_par    = d_in[18];
  const void* mo_w     = d_in[19];

  float* wsf    = (float*)d_ws;
  float* xdbl   = wsf + OFF_XDBL;
  float* hin    = wsf + OFF_R1;
  bf16*  wsw_b  = (bf16*)(wsf + OFF_WSW);
  bf16*  u_b    = (bf16*)(wsf + OFF_U);
  bf16*  xpre_b = (bf16*)(wsf + OFF_R2);
  bf16*  siluz_b= (bf16*)(wsf + OFF_SILUZ);
  bf16*  xc_b   = (bf16*)(wsf + OFF_XC);
  bf16*  g_b    = (bf16*)(wsf + OFF_G);
  int*   flagp  = (int*)(wsf + OFF_FLAG);
  int*   cntp   = (int*)(wsf + OFF_CNT);
  int*   sflag  = (int*)(wsf + OFF_SFLAG);

  prep_k<<<dim3(592), dim3(256), 0, stream>>>(W_ip, W_wp, W_fp, in_proj, mo_w, W_op,
                                              x_proj, dt_projw, x, wsf, flagp, cntp);
  fm_k<<<dim3(NTOK / 32), dim3(256), 0, stream>>>(x, w_norm1, wsf, b_ip, b_wp, b_fp,
                                                  wsw_b, u_b, xpre_b, siluz_b, flagp);
  conv_k<<<dim3(NTOK / 32), dim3(256), 0, stream>>>(xpre_b, conv_w, conv_b, wsf, xc_b, xdbl, flagp);
  scan1_k<<<dim3(64 * NCHUNK), dim3(256), 0, stream>>>(xdbl, xc_b, siluz_b, A_log, D_par,
                                                       dt_projb, wsf + OFF_WDT, hin, sflag,
                                                       cntp, g_b, flagp);
  back_k<<<dim3(NTOK / 32), dim3(256), 0, stream>>>(g_b, wsf, w_norm2, u_b, wsw_b, b_op, x, d_out, flagp);
}

// Round 9
// 208.371 us; speedup vs baseline: 8.8598x; 8.8598x over previous
//
#include <hip/hip_runtime.h>
#include <hip/hip_bf16.h>

typedef __hip_bfloat16 bf16;
typedef __attribute__((ext_vector_type(8))) short bf16x8;
typedef __attribute__((ext_vector_type(4))) float f32x4;
#define DEV __device__ __forceinline__

constexpr int SEQ  = 4096;
constexpr int NB   = 4;
constexpr int NTOK = NB * SEQ;          // 16384 tokens
constexpr float EPS = 1e-5f;
constexpr int NCH = 64;                 // scan chunk length
constexpr int NCHUNK = SEQ / NCH;       // 64 chunks/seq
constexpr float LOG2E = 1.44269504f;

// ---------------- workspace layout (float offsets) ----------------
constexpr int OFF_WDT  = 0;                    // f32 [8][256] dt_proj^T
constexpr int OFF_WB   = 2048;                 // bf16 weight area (151552 shorts)
constexpr int WB_IP = 0;                       // [128][64]
constexpr int WB_WP = 8192;                    // [128][64]
constexpr int WB_FP = 16384;                   // [128][128]
constexpr int WB_PR = 32768;                   // [512][128]
constexpr int WB_MO = 98304;                   // [128][256]
constexpr int WB_OP = 131072;                  // [64][128]
constexpr int WB_XP = 139264;                  // [48][256] (40 real + 8 zero rows)
constexpr int WB_TOT = 151552;
constexpr int OFF_XDBL = OFF_WB + WB_TOT / 2;        // f32 [NTOK][40] (655360 f)
constexpr int OFF_R1   = OFF_XDBL + NTOK * 40;       // hinit (1048576 f)
constexpr int OFF_WSW  = OFF_R1   + 1048576;         // bf16 NTOK*128  -> 1048576 f
constexpr int OFF_U    = OFF_WSW  + 1048576;         // bf16 NTOK*128  -> 1048576 f
constexpr int OFF_R2   = OFF_U    + 1048576;         // xpre / summ    (2097152 f)
constexpr int OFF_SILUZ= OFF_R2   + 2097152;         // bf16 NTOK*256  -> 2097152 f
constexpr int OFF_XC   = OFF_SILUZ+ 2097152;         // bf16 NTOK*256
constexpr int OFF_G    = OFF_XC   + 2097152;         // bf16 NTOK*256
constexpr int OFF_FLAG = OFF_G    + 2097152;         // int dtype flag

DEV float b2f(bf16 x) { return __bfloat162float(x); }
DEV bf16 f2b(float x) { return __float2bfloat16(x); }
DEV short shof(bf16 h) { short s; __builtin_memcpy(&s, &h, 2); return s; }
DEV float ldin(const void* p, int i, int f) {
  return f ? ((const float*)p)[i] : b2f(((const bf16*)p)[i]);
}
DEV unsigned pack2(float a, float b) {
  bf16 ha = f2b(a), hb = f2b(b);
  unsigned short ua, ub;
  __builtin_memcpy(&ua, &ha, 2); __builtin_memcpy(&ub, &hb, 2);
  return (unsigned)ua | ((unsigned)ub << 16);
}
DEV float lo16f(unsigned u) { return __int_as_float((int)(u << 16)); }
DEV float hi16f(unsigned u) { return __int_as_float((int)(u & 0xffff0000u)); }
template<int CTRL>
DEV float dpp_add(float v) {
  int r = __builtin_amdgcn_update_dpp(0, __float_as_int(v), CTRL, 0xF, 0xF, false);
  return v + __int_as_float(r);
}
DEV float exp2f_fast(float a) { return __builtin_amdgcn_exp2f(a); }
DEV float softplus(float a) {
  return (a > 20.f) ? a : __logf(1.f + exp2f_fast(a * LOG2E));
}
DEV float silu(float a) { return a / (1.f + __expf(-a)); }

// ---------------- prep: inline dtype detect + bf16 weight copies + WDT f32 ----------------
DEV void cpw(int e, int base, int count, const void* __restrict__ src,
             bf16* __restrict__ wb, int f) {
  int r = e - base;
  if (r >= 0 && r < count) wb[base + r] = f2b(ldin(src, r, f));
}
__global__ __launch_bounds__(256) void prep_k(
    const void* __restrict__ w_ip, const void* __restrict__ w_wp, const void* __restrict__ w_fp,
    const void* __restrict__ w_pr, const void* __restrict__ w_mo, const void* __restrict__ w_op,
    const void* __restrict__ w_x,  const void* __restrict__ w_dt,
    const void* __restrict__ x, float* __restrict__ wsf, int* __restrict__ flagp)
{
  __shared__ int cnt;
  if (threadIdx.x == 0) cnt = 0;
  __syncthreads();
  {
    float v = b2f(((const bf16*)x)[threadIdx.x]);
    int ok = (v == v) && fabsf(v) > 1e-4f && fabsf(v) < 100.f;
    atomicAdd(&cnt, ok);
  }
  __syncthreads();
  int f = (cnt > 204) ? 0 : 1;
  if (blockIdx.x == 0 && threadIdx.x == 0) *flagp = f;

  int e = blockIdx.x * 256 + threadIdx.x;   // 592*256 covers 151552
  bf16* wb = (bf16*)(wsf + OFF_WB);
  cpw(e, WB_IP, 8192,  w_ip, wb, f);
  cpw(e, WB_WP, 8192,  w_wp, wb, f);
  cpw(e, WB_FP, 16384, w_fp, wb, f);
  cpw(e, WB_PR, 65536, w_pr, wb, f);
  cpw(e, WB_MO, 32768, w_mo, wb, f);
  cpw(e, WB_OP, 8192,  w_op, wb, f);
  {
    int r = e - WB_XP;
    if (r >= 0 && r < 12288) wb[WB_XP + r] = (r < 10240) ? f2b(ldin(w_x, r, f)) : f2b(0.f);
  }
  if (e < 2048) {
    int r = e >> 8, d = e & 255;
    wsf[OFF_WDT + e] = ldin(w_dt, d * 8 + r, f);
  }
}

// ---------------- fm: rms1 + ip/wp GEMMs + fp GEMM + in_proj GEMM ----------------
__global__ __launch_bounds__(256) void fm_k(
    const void* __restrict__ x, const void* __restrict__ w1, const float* __restrict__ wsf,
    const void* __restrict__ b_ip, const void* __restrict__ b_wp, const void* __restrict__ b_fp,
    bf16* __restrict__ wsw, bf16* __restrict__ u, bf16* __restrict__ xpre,
    bf16* __restrict__ siluz, const int* __restrict__ flagp)
{
  __shared__ short xn[32 * 72];
  __shared__ short t1[32 * 136];
  __shared__ short ul[32 * 136];
  const int f = *flagp;
  const int tid = threadIdx.x;
  const int tok0 = blockIdx.x * 32;
  {  // rms1: 8 threads/token, 8 ch each
    const int token = tid >> 3, r = tid & 7;
    float v[8]; float ss = 0.f;
    #pragma unroll
    for (int k = 0; k < 8; ++k) {
      v[k] = ldin(x, (tok0 + token) * 64 + r * 8 + k, f);
      ss += v[k] * v[k];
    }
    ss += __shfl_xor(ss, 1, 8); ss += __shfl_xor(ss, 2, 8); ss += __shfl_xor(ss, 4, 8);
    float sc = rsqrtf(ss * (1.f / 64.f) + EPS);
    unsigned* dst = (unsigned*)xn + token * 36 + r * 4;
    #pragma unroll
    for (int k = 0; k < 4; ++k) {
      int i = r * 8 + k * 2;
      dst[k] = pack2(v[k*2] * sc * ldin(w1, i, f), v[k*2+1] * sc * ldin(w1, i + 1, f));
    }
  }
  __syncthreads();
  const int lane = tid & 63, m = lane & 15, q = lane >> 4;
  const int w = tid >> 6;
  {  // GEMM1/1b: K=64, N=128 each. waves 0,1 -> Wip (t1), 2,3 -> Wwp (wsw)
    const int wt = w >> 1, ng = w & 1;
    const bf16* W = (const bf16*)(wsf + OFF_WB) + (wt ? WB_WP : WB_IP);
    const void* bia = wt ? b_wp : b_ip;
    bf16x8 a[2][2];
    #pragma unroll
    for (int mt = 0; mt < 2; ++mt)
      #pragma unroll
      for (int kk = 0; kk < 2; ++kk)
        a[mt][kk] = *(const bf16x8*)&xn[(mt * 16 + m) * 72 + kk * 32 + q * 8];
    #pragma unroll
    for (int nti = 0; nti < 4; ++nti) {
      int nt = ng * 4 + nti;
      int n = nt * 16 + m;
      f32x4 acc[2] = {{0,0,0,0},{0,0,0,0}};
      #pragma unroll
      for (int kk = 0; kk < 2; ++kk) {
        bf16x8 b = *(const bf16x8*)(W + (nt * 16 + m) * 64 + kk * 32 + q * 8);
        #pragma unroll
        for (int mt = 0; mt < 2; ++mt)
          acc[mt] = __builtin_amdgcn_mfma_f32_16x16x32_bf16(a[mt][kk], b, acc[mt], 0, 0, 0);
      }
      float bv = ldin(bia, n, f);
      #pragma unroll
      for (int mt = 0; mt < 2; ++mt)
        #pragma unroll
        for (int r = 0; r < 4; ++r) {
          float v = acc[mt][r] + bv;
          if (wt) wsw[(tok0 + mt * 16 + q * 4 + r) * 128 + n] = f2b(silu(v));
          else    t1[(mt * 16 + q * 4 + r) * 136 + n] = shof(f2b(v));
        }
    }
  }
  __syncthreads();
  {  // GEMM2: u = t1@Wfp^T + b_fp. K=128, N=128; wave w -> nt {2w, 2w+1}
    const bf16* WF = (const bf16*)(wsf + OFF_WB) + WB_FP;
    bf16x8 a[2][4];
    #pragma unroll
    for (int mt = 0; mt < 2; ++mt)
      #pragma unroll
      for (int kk = 0; kk < 4; ++kk)
        a[mt][kk] = *(const bf16x8*)&t1[(mt * 16 + m) * 136 + kk * 32 + q * 8];
    #pragma unroll
    for (int nti = 0; nti < 2; ++nti) {
      int nt = w * 2 + nti;
      int n = nt * 16 + m;
      f32x4 acc[2] = {{0,0,0,0},{0,0,0,0}};
      #pragma unroll
      for (int kk = 0; kk < 4; ++kk) {
        bf16x8 b = *(const bf16x8*)(WF + (nt * 16 + m) * 128 + kk * 32 + q * 8);
        #pragma unroll
        for (int mt = 0; mt < 2; ++mt)
          acc[mt] = __builtin_amdgcn_mfma_f32_16x16x32_bf16(a[mt][kk], b, acc[mt], 0, 0, 0);
      }
      float bv = ldin(b_fp, n, f);
      #pragma unroll
      for (int mt = 0; mt < 2; ++mt)
        #pragma unroll
        for (int r = 0; r < 4; ++r) {
          bf16 h = f2b(acc[mt][r] + bv);
          ul[(mt * 16 + q * 4 + r) * 136 + n] = shof(h);
          u[(tok0 + mt * 16 + q * 4 + r) * 128 + n] = h;
        }
    }
  }
  __syncthreads();
  {  // GEMM3: xz = u@Wpr^T. K=128, N=512; wave w -> nt [8w, 8w+8)
    const bf16* WP = (const bf16*)(wsf + OFF_WB) + WB_PR;
    bf16x8 a[2][4];
    #pragma unroll
    for (int mt = 0; mt < 2; ++mt)
      #pragma unroll
      for (int kk = 0; kk < 4; ++kk)
        a[mt][kk] = *(const bf16x8*)&ul[(mt * 16 + m) * 136 + kk * 32 + q * 8];
    #pragma unroll
    for (int nti = 0; nti < 8; ++nti) {
      int nt = w * 8 + nti;
      int n = nt * 16 + m;
      f32x4 acc[2] = {{0,0,0,0},{0,0,0,0}};
      #pragma unroll
      for (int kk = 0; kk < 4; ++kk) {
        bf16x8 b = *(const bf16x8*)(WP + (nt * 16 + m) * 128 + kk * 32 + q * 8);
        #pragma unroll
        for (int mt = 0; mt < 2; ++mt)
          acc[mt] = __builtin_amdgcn_mfma_f32_16x16x32_bf16(a[mt][kk], b, acc[mt], 0, 0, 0);
      }
      #pragma unroll
      for (int mt = 0; mt < 2; ++mt)
        #pragma unroll
        for (int r = 0; r < 4; ++r) {
          int tok = tok0 + mt * 16 + q * 4 + r;
          if (n < 256) xpre[tok * 256 + n] = f2b(acc[mt][r]);
          else         siluz[tok * 256 + (n - 256)] = f2b(silu(acc[mt][r]));
        }
    }
  }
}

// ---------------- conv (depthwise w4 + silu) + x_proj MFMA -> xc, xdbl ----------------
__global__ __launch_bounds__(256) void conv_k(
    const bf16* __restrict__ xpre, const void* __restrict__ cw, const void* __restrict__ cb,
    const float* __restrict__ wsf, bf16* __restrict__ xc, float* __restrict__ xdbl,
    const int* __restrict__ flagp)
{
  __shared__ short xh[35 * 256];
  __shared__ short cs[32 * 264];
  const int f = *flagp;
  const int tid = threadIdx.x;
  const int tok0 = blockIdx.x * 32;
  const bool seqstart = (tok0 & (SEQ - 1)) == 0;
  for (int c = tid; c < 1120; c += 256) {
    int e0 = c * 8;
    int tt = e0 >> 8, i = e0 & 255;
    int gtok = tok0 + tt - 3;
    uint4* dst = (uint4*)(xh + e0);
    if (gtok >= 0 && !(seqstart && tt < 3)) *dst = *(const uint4*)(xpre + gtok * 256 + i);
    else                                    *dst = make_uint4(0, 0, 0, 0);
  }
  __syncthreads();
  {
    const int ch0 = (tid & 63) * 4;
    const int t0 = (tid >> 6) * 8;
    float w4[4][4], cb4[4];
    #pragma unroll
    for (int c = 0; c < 4; ++c) {
      cb4[c] = ldin(cb, ch0 + c, f);
      #pragma unroll
      for (int k = 0; k < 4; ++k) w4[c][k] = ldin(cw, (ch0 + c) * 4 + k, f);
    }
    float win[11][4];
    #pragma unroll
    for (int r = 0; r < 11; ++r) {
      uint2 v = *(const uint2*)&xh[(t0 + r) * 256 + ch0];
      win[r][0] = lo16f(v.x); win[r][1] = hi16f(v.x);
      win[r][2] = lo16f(v.y); win[r][3] = hi16f(v.y);
    }
    #pragma unroll
    for (int t = 0; t < 8; ++t) {
      unsigned pk[2];
      #pragma unroll
      for (int cp = 0; cp < 2; ++cp) {
        float o[2];
        #pragma unroll
        for (int ci = 0; ci < 2; ++ci) {
          int c = cp * 2 + ci;
          float acc = cb4[c];
          #pragma unroll
          for (int k = 0; k < 4; ++k) acc = fmaf(win[t + k][c], w4[c][k], acc);
          o[ci] = silu(acc);
        }
        pk[cp] = pack2(o[0], o[1]);
      }
      uint2 pv = make_uint2(pk[0], pk[1]);
      *(uint2*)&cs[(t0 + t) * 264 + ch0] = pv;
      *(uint2*)(xc + (tok0 + t0 + t) * 256 + ch0) = pv;
    }
  }
  __syncthreads();
  const int w = tid >> 6;
  if (w < 2) {
    const bf16* Wx = (const bf16*)(wsf + OFF_WB) + WB_XP;
    const int lane = tid & 63, m = lane & 15, quad = lane >> 4;
    f32x4 acc[3] = {{0,0,0,0},{0,0,0,0},{0,0,0,0}};
    #pragma unroll
    for (int k0 = 0; k0 < 256; k0 += 32) {
      bf16x8 af = *(const bf16x8*)&cs[(w * 16 + m) * 264 + k0 + quad * 8];
      #pragma unroll
      for (int nt = 0; nt < 3; ++nt) {
        bf16x8 bfr = *(const bf16x8*)(Wx + (nt * 16 + m) * 256 + k0 + quad * 8);
        acc[nt] = __builtin_amdgcn_mfma_f32_16x16x32_bf16(af, bfr, acc[nt], 0, 0, 0);
      }
    }
    #pragma unroll
    for (int nt = 0; nt < 3; ++nt) {
      int n = nt * 16 + m;
      if (n < 40) {
        #pragma unroll
        for (int r = 0; r < 4; ++r)
          xdbl[(tok0 + w * 16 + quad * 4 + r) * 40 + n] = acc[nt][r];
      }
    }
  }
}

// ---------------- chunked selective scan (two-pass; du prestaged, D-term in epilogue) ----------------
template<bool IS_C>
__global__ __launch_bounds__(256) void scan_k(
    const float* __restrict__ xdbl, const bf16* __restrict__ xc, const bf16* __restrict__ siluz,
    const void* __restrict__ A_log, const void* __restrict__ D_par, const void* __restrict__ dt_b,
    const float* __restrict__ WDT, float* __restrict__ summ, const float* __restrict__ hinit,
    bf16* __restrict__ g, const int* __restrict__ flagp)
{
  const int f = *flagp;
  const int tid = threadIdx.x;
  const int bb = blockIdx.x >> 4, dg = blockIdx.x & 15, c = blockIdx.y;
  const int dl = tid >> 4, s = tid & 15;
  const int j = s;
  const int d_loop = dg * 16 + dl;
  const int d_stg  = dg * 16 + j;
  const int tok_base = bb * SEQ + c * NCH;

  __shared__ float dt_l[NCH * 8];
  __shared__ float dx_l[NCH * 16 * 2];   // (delta, du) pairs
  __shared__ float bc_l[IS_C ? NCH * 16 * 2 : NCH * 16];
  __shared__ float g_l[IS_C ? NCH * 16 : 1];

  // Aval2 = -exp(A_log) * log2(e): dA = 2^(dlt*Aval2)
  const float Aval2 = -__expf(ldin(A_log, d_loop * 16 + s, f)) * LOG2E;
  const float Dp_stg = ldin(D_par, d_stg, f);
  const float dtb_j = ldin(dt_b, d_stg, f);
  float wdt[8];
  #pragma unroll
  for (int r = 0; r < 8; ++r) wdt[r] = WDT[r * 256 + d_stg];

  const int sidx = (blockIdx.x * NCHUNK + c) * 256 + tid;
  float h = IS_C ? hinit[sidx] : 0.f;
  float sdlt = 0.f;

  for (int e2 = tid * 4; e2 < NCH * 8; e2 += 1024)
    *(float4*)(dt_l + e2) = *(const float4*)(xdbl + (tok_base + (e2 >> 3)) * 40 + (e2 & 7));
  #pragma unroll
  for (int k = 0; k < 4; ++k) {
    int e = tid + k * 256;
    int t = e >> 4;
    int tok = tok_base + t;
    float B = xdbl[tok * 40 + 8 + j];
    if (IS_C) {
      bc_l[e * 2 + 0] = B;
      bc_l[e * 2 + 1] = xdbl[tok * 40 + 24 + j];
    } else bc_l[e] = B;
  }
  __syncthreads();
  #pragma unroll
  for (int k = 0; k < 4; ++k) {
    int e = tid + k * 256;
    int t = e >> 4;
    float a = dtb_j;
    #pragma unroll
    for (int r = 0; r < 8; ++r) a = fmaf(dt_l[t * 8 + r], wdt[r], a);
    float dlt = softplus(a);
    float xcv = b2f(xc[(tok_base + t) * 256 + d_stg]);
    *(float2*)(dx_l + e * 2) = make_float2(dlt, dlt * xcv);   // (delta, du)
  }
  __syncthreads();

  #pragma unroll 8
  for (int t = 0; t < NCH; ++t) {
    float2 dx = *(const float2*)(dx_l + (t * 16 + dl) * 2);   // (dlt, du)
    float dA = exp2f_fast(dx.x * Aval2);
    if (!IS_C) sdlt += dx.x;
    if (IS_C) {
      float2 bc = *(const float2*)(bc_l + (t * 16 + s) * 2);
      h = fmaf(dA, h, dx.y * bc.x);
      float p = h * bc.y;
      p = dpp_add<0x121>(p);
      p = dpp_add<0x122>(p);
      p = dpp_add<0x124>(p);
      p = dpp_add<0x128>(p);
      if (s == 0) g_l[t * 16 + dl] = p;
    } else {
      h = fmaf(dA, h, dx.y * bc_l[t * 16 + s]);
    }
  }
  if (IS_C) {
    __syncthreads();
    #pragma unroll
    for (int k = 0; k < 4; ++k) {
      int e = tid + k * 256;
      int t = e >> 4;
      int tok = tok_base + t;
      float xcv = b2f(xc[tok * 256 + d_stg]);
      g[tok * 256 + d_stg] = f2b((g_l[e] + xcv * Dp_stg) * b2f(siluz[tok * 256 + d_stg]));
    }
  } else {
    *(float2*)(summ + sidx * 2) = make_float2(exp2f_fast(Aval2 * sdlt), h);
  }
}

// phase B: exclusive scan over chunk summaries, 16-deep load batching
__global__ __launch_bounds__(256) void scanB_k(const float* __restrict__ summ, float* __restrict__ hinit) {
  int bx = blockIdx.x, qq = threadIdx.x;
  float h = 0.f;
  for (int c0 = 0; c0 < NCHUNK; c0 += 16) {
    float2 sv[16];
    #pragma unroll
    for (int k = 0; k < 16; ++k)
      sv[k] = *(const float2*)(summ + ((bx * NCHUNK + c0 + k) * 256 + qq) * 2);
    #pragma unroll
    for (int k = 0; k < 16; ++k) {
      hinit[(bx * NCHUNK + c0 + k) * 256 + qq] = h;
      h = fmaf(sv[k].x, h, sv[k].y);
    }
  }
}

// ---------------- back: m = g@Wmo^T ; rms2+u, gate wsw ; @Wop^T + b + resid ----------------
__global__ __launch_bounds__(256) void back_k(
    const bf16* __restrict__ g, const float* __restrict__ wsf, const void* __restrict__ w2,
    const bf16* __restrict__ u, const bf16* __restrict__ wsw, const void* __restrict__ b_op,
    const void* __restrict__ x, void* __restrict__ out, const int* __restrict__ flagp)
{
  __shared__ short ms[32 * 136];
  const int f = *flagp;
  const int tid = threadIdx.x;
  const int tok0 = blockIdx.x * 32;
  const int lane = tid & 63, m = lane & 15, q = lane >> 4;
  const int w = tid >> 6;
  const bf16* WM = (const bf16*)(wsf + OFF_WB) + WB_MO;
  const bf16* WO = (const bf16*)(wsf + OFF_WB) + WB_OP;
  {  // phase 1: m = g@Wmo^T (K=256, N=128); wave w -> nt {2w, 2w+1}
    f32x4 acc[2][2] = {{{0,0,0,0},{0,0,0,0}},{{0,0,0,0},{0,0,0,0}}};
    #pragma unroll
    for (int kk = 0; kk < 8; ++kk) {
      bf16x8 a0 = *(const bf16x8*)(g + (tok0 + m) * 256 + kk * 32 + q * 8);
      bf16x8 a1 = *(const bf16x8*)(g + (tok0 + 16 + m) * 256 + kk * 32 + q * 8);
      #pragma unroll
      for (int nti = 0; nti < 2; ++nti) {
        int nt = w * 2 + nti;
        bf16x8 b = *(const bf16x8*)(WM + (nt * 16 + m) * 256 + kk * 32 + q * 8);
        acc[nti][0] = __builtin_amdgcn_mfma_f32_16x16x32_bf16(a0, b, acc[nti][0], 0, 0, 0);
        acc[nti][1] = __builtin_amdgcn_mfma_f32_16x16x32_bf16(a1, b, acc[nti][1], 0, 0, 0);
      }
    }
    #pragma unroll
    for (int nti = 0; nti < 2; ++nti) {
      int n = (w * 2 + nti) * 16 + m;
      #pragma unroll
      for (int mt = 0; mt < 2; ++mt)
        #pragma unroll
        for (int r = 0; r < 4; ++r)
          ms[(mt * 16 + q * 4 + r) * 136 + n] = shof(f2b(acc[nti][mt][r]));
    }
  }
  __syncthreads();
  {  // rms2 + u residual + wsw gate (8 threads/token, 16 ch each)
    const int token = tid >> 3, r = tid & 7;
    float mv[16]; float ss = 0.f;
    #pragma unroll
    for (int k = 0; k < 16; ++k) {
      mv[k] = b2f(((const bf16*)ms)[token * 136 + r * 16 + k]);
      ss += mv[k] * mv[k];
    }
    ss += __shfl_xor(ss, 1, 8); ss += __shfl_xor(ss, 2, 8); ss += __shfl_xor(ss, 4, 8);
    float sc = rsqrtf(ss * (1.f / 128.f) + EPS);
    #pragma unroll
    for (int k = 0; k < 16; ++k) {
      int i = r * 16 + k;
      int ga = (tok0 + token) * 128 + i;
      float v = mv[k] * sc * ldin(w2, i, f) + b2f(u[ga]);
      ms[token * 136 + i] = shof(f2b(v * b2f(wsw[ga])));
    }
  }
  __syncthreads();
  {  // phase 2: out = ms@Wop^T + b_op + resid (K=128, N=64); wave w -> nt w
    bf16x8 a[2][4];
    #pragma unroll
    for (int mt = 0; mt < 2; ++mt)
      #pragma unroll
      for (int kk = 0; kk < 4; ++kk)
        a[mt][kk] = *(const bf16x8*)&ms[(mt * 16 + m) * 136 + kk * 32 + q * 8];
    int nt = w;
    f32x4 acc[2] = {{0,0,0,0},{0,0,0,0}};
    #pragma unroll
    for (int kk = 0; kk < 4; ++kk) {
      bf16x8 b = *(const bf16x8*)(WO + (nt * 16 + m) * 128 + kk * 32 + q * 8);
      #pragma unroll
      for (int mt = 0; mt < 2; ++mt)
        acc[mt] = __builtin_amdgcn_mfma_f32_16x16x32_bf16(a[mt][kk], b, acc[mt], 0, 0, 0);
    }
    int n = nt * 16 + m;
    float bv = ldin(b_op, n, f);
    #pragma unroll
    for (int mt = 0; mt < 2; ++mt)
      #pragma unroll
      for (int r = 0; r < 4; ++r) {
        int token = tok0 + mt * 16 + q * 4 + r;
        float v = acc[mt][r] + bv + ldin(x, token * 64 + n, f);
        if (f) ((float*)out)[token * 64 + n] = v;
        else   ((bf16*)out)[token * 64 + n] = f2b(v);
      }
  }
}

// ---------------- launch ----------------
extern "C" void kernel_launch(void* const* d_in, const int* in_sizes, int n_in,
                              void* d_out, int out_size, void* d_ws, size_t ws_size,
                              hipStream_t stream) {
  (void)in_sizes; (void)n_in; (void)out_size; (void)ws_size;
  const void* x        = d_in[0];
  const void* w_norm1  = d_in[1];
  const void* w_norm2  = d_in[2];
  const void* W_ip     = d_in[3];
  const void* b_ip     = d_in[4];
  const void* W_fp     = d_in[5];
  const void* b_fp     = d_in[6];
  const void* W_wp     = d_in[7];
  const void* b_wp     = d_in[8];
  const void* W_op     = d_in[9];
  const void* b_op     = d_in[10];
  const void* in_proj  = d_in[11];
  const void* conv_w   = d_in[12];
  const void* conv_b   = d_in[13];
  const void* x_proj   = d_in[14];
  const void* dt_projw = d_in[15];
  const void* dt_projb = d_in[16];
  const void* A_log    = d_in[17];
  const void* D_par    = d_in[18];
  const void* mo_w     = d_in[19];

  float* wsf    = (float*)d_ws;
  float* xdbl   = wsf + OFF_XDBL;
  float* hin    = wsf + OFF_R1;
  bf16*  wsw_b  = (bf16*)(wsf + OFF_WSW);
  bf16*  u_b    = (bf16*)(wsf + OFF_U);
  bf16*  xpre_b = (bf16*)(wsf + OFF_R2);
  float* summ   = wsf + OFF_R2;
  bf16*  siluz_b= (bf16*)(wsf + OFF_SILUZ);
  bf16*  xc_b   = (bf16*)(wsf + OFF_XC);
  bf16*  g_b    = (bf16*)(wsf + OFF_G);
  int*   flagp  = (int*)(wsf + OFF_FLAG);

  prep_k<<<dim3(592), dim3(256), 0, stream>>>(W_ip, W_wp, W_fp, in_proj, mo_w, W_op,
                                              x_proj, dt_projw, x, wsf, flagp);
  fm_k<<<dim3(NTOK / 32), dim3(256), 0, stream>>>(x, w_norm1, wsf, b_ip, b_wp, b_fp,
                                                  wsw_b, u_b, xpre_b, siluz_b, flagp);
  conv_k<<<dim3(NTOK / 32), dim3(256), 0, stream>>>(xpre_b, conv_w, conv_b, wsf, xc_b, xdbl, flagp);
  scan_k<false><<<dim3(64, NCHUNK), dim3(256), 0, stream>>>(xdbl, xc_b, siluz_b, A_log, D_par,
                                                            dt_projb, wsf + OFF_WDT, summ, hin, g_b, flagp);
  scanB_k<<<dim3(64), dim3(256), 0, stream>>>(summ, hin);
  scan_k<true><<<dim3(64, NCHUNK), dim3(256), 0, stream>>>(xdbl, xc_b, siluz_b, A_log, D_par,
                                                           dt_projb, wsf + OFF_WDT, summ, hin, g_b, flagp);
  back_k<<<dim3(NTOK / 32), dim3(256), 0, stream>>>(g_b, wsf, w_norm2, u_b, wsw_b, b_op, x, d_out, flagp);
}